// Round 7
// baseline (81.749 us; speedup 1.0000x reference)
//
#include <hip/hip_runtime.h>
#include <cmath>
#include <complex>
#include <algorithm>

#define NW      1022
#define NB      64
#define TLEN    17150   /* HOP*(F-1)+W */
#define PADL    18
#define LXLEN   17186   /* TLEN + 2*PADL */
#define NFRAMES 4096    /* NB*64 */
#define GK      1024    /* padded K for both GEMMs */
#define BS      4288    /* samples per oa_iir split (4 splits/row) */
#define SPAN    4480    /* LDS floats per buffer in oa_iir */

typedef __attribute__((ext_vector_type(8))) short short8;
typedef __attribute__((ext_vector_type(4))) float floatx4;

struct IirCoef {
  float b0,b1,b2,b3,b4,b5;
  float a1,a2,a3,a4,a5;
  float zi0,zi1,zi2,zi3,zi4;
};

static __device__ __forceinline__ ushort f2bf(float f) {
  uint32_t u = __builtin_bit_cast(uint32_t, f);
  uint32_t r = (u + 0x7FFFu + ((u >> 16) & 1u)) >> 16;   // RNE
  return (ushort)r;
}
static __device__ __forceinline__ float bf2f(ushort u) {
  return __builtin_bit_cast(float, (uint32_t)u << 16);
}

// fp32-exact (k*t) mod 1022 (k<=511, t<=1021: k*t < 2^24), then radians
static __device__ __forceinline__ float phase_mod(int k, int t) {
  const float TPN = 6.2831853071795864769f / 1022.f;
  float kt = (float)(k * t);
  float q = floorf(kt * (1.0f / 1022.0f));
  float r = kt - q * 1022.0f;
  if (r < 0.f) r += 1022.f;
  if (r >= 1022.f) r -= 1022.f;
  return r * TPN;
}

// ---------------- fused prep: BT1 | BT2 | A1-transpose ----------------
// blocks [0,4096): BT1[t][kk] (irfft basis * syn); [4096,8192): BT2[kk][t]
// (rfft basis * fwd win); [8192,9216): A1 transpose tiles
__global__ __launch_bounds__(256) void prep(const float* __restrict__ x,
                                            ushort* __restrict__ BT1,
                                            ushort* __restrict__ BT2,
                                            ushort* __restrict__ A1) {
  __shared__ float tile[32][129];
  const float TPN = 6.2831853071795864769f / 1022.f;
  int bid = blockIdx.x;
  if (bid < 4096) {
    int idx = bid * 256 + threadIdx.x;        // BT1[t][kk]
    int t = idx >> 10, kk = idx & 1023;
    int k = kk & 511;
    float val = 0.f;
    if (t < NW) {
      float fw = 0.5f - 0.5f * __cosf((float)t * TPN);
      float den = 0.f;
      int tm = t & 255;
      #pragma unroll
      for (int j = 0; j < 4; ++j) {
        int u = tm + (j << 8);
        if (u < NW) { float w = 0.5f - 0.5f * __cosf((float)u * TPN); den += w * w; }
      }
      float syn = fw / den;
      float arg = phase_mod(k, t);
      float scale = (k == 0 || k == 511) ? 1.f : 2.f;
      if (kk < 512) val = __cosf(arg) * scale * (1.f / 1022.f) * syn;
      else          val = (k == 0 || k == 511) ? 0.f
                          : -__sinf(arg) * scale * (1.f / 1022.f) * syn;
    }
    BT1[idx] = f2bf(val);
  } else if (bid < 8192) {
    int idx = (bid - 4096) * 256 + threadIdx.x;  // BT2[kk][t]
    int kk = idx >> 10, t = idx & 1023;
    int k = kk & 511;
    float val = 0.f;
    if (t < NW) {
      float fw = 0.5f - 0.5f * __cosf((float)t * TPN);
      float arg = phase_mod(k, t);
      val = (kk < 512) ? fw * __cosf(arg) : -fw * __sinf(arg);
    }
    BT2[idx] = f2bf(val);
  } else {
    int tb = bid - 8192;
    int b  = tb >> 4;
    int k0 = (tb & 15) << 5;
    int tid = threadIdx.x;
    #pragma unroll
    for (int e = 0; e < 16; ++e) {
      int lin = tid + e * 256;
      int i = lin >> 7, c = lin & 127;
      tile[i][c] = x[(b * 512 + k0 + i) * 128 + c];
    }
    __syncthreads();
    #pragma unroll
    for (int e = 0; e < 16; ++e) {
      int lin = tid + e * 256;
      int c = lin >> 5, i = lin & 31;
      int f = c >> 1, ri = c & 1;
      A1[(b * 64 + f) * 1024 + ri * 512 + k0 + i] = f2bf(tile[i][c]);
    }
  }
}

// ---------------- shared GEMM pieces ----------------
#define GLOAD16(gsrc, ldst) \
  __builtin_amdgcn_global_load_lds( \
      (const __attribute__((address_space(1))) void*)(gsrc), \
      (__attribute__((address_space(3))) void*)(ldst), 16, 0, 0)

#define WAIT_VMCNT6()  __builtin_amdgcn_s_waitcnt(0xF76)  /* vmcnt(6) */
#define WAIT_VMCNT0()  __builtin_amdgcn_s_waitcnt(0xF70)  /* vmcnt(0) */

// wave-tile 32x64: acc[2][4]
static __device__ __forceinline__ void gemm_compute64(
    const ushort* as, const ushort* bs, int arow, int brow, int g, int rx,
    floatx4 (&acc)[2][4]) {
  #pragma unroll
  for (int ks = 0; ks < 2; ++ks) {
    short8 af[2], bfr[4];
    const int chunk = ((ks << 2) + g) ^ rx;
    #pragma unroll
    for (int fm = 0; fm < 2; ++fm)
      af[fm] = *(const short8*)(as + (arow + fm * 16) * 64 + chunk * 8);
    #pragma unroll
    for (int fn = 0; fn < 4; ++fn)
      bfr[fn] = *(const short8*)(bs + (brow + fn * 16) * 64 + chunk * 8);
    #pragma unroll
    for (int fm = 0; fm < 2; ++fm)
      #pragma unroll
      for (int fn = 0; fn < 4; ++fn)
        acc[fm][fn] = __builtin_amdgcn_mfma_f32_16x16x32_bf16(
            af[fm], bfr[fn], acc[fm][fn], 0, 0, 0);
  }
}

// ---- GEMM1: frames(bf16)[4096,1024] = A1[4096,1024] * BT1^T ----
__global__ __launch_bounds__(256, 3) void gemm1(
    const ushort* __restrict__ A, const ushort* __restrict__ Bt,
    ushort* __restrict__ Fr) {
  __shared__ __align__(16) ushort As[2][64 * 64];
  __shared__ __align__(16) ushort Bs[2][128 * 64];
  const int tid = threadIdx.x;
  const int wid = tid >> 6, lane = tid & 63;
  const int m0 = blockIdx.y * 64, n0 = blockIdx.x * 128;
  const int warp_m = wid >> 1, warp_n = wid & 1;

  floatx4 acc[2][4];
  #pragma unroll
  for (int i = 0; i < 2; ++i)
    #pragma unroll
    for (int j = 0; j < 4; ++j) acc[i][j] = (floatx4){0.f, 0.f, 0.f, 0.f};

  const int lr = lane >> 3, lc = lane & 7;
  const int swz = lc ^ lr;
  const ushort* aBase = A  + (size_t)(m0 + wid * 8 + lr) * GK + swz * 8;
  const ushort* bBase = Bt + (size_t)(n0 + wid * 8 + lr) * GK + swz * 8;

  const int lane15 = lane & 15;
  const int g = lane >> 4;
  const int rx = lane & 7;
  const int arow = warp_m * 32 + lane15;
  const int brow = warp_n * 64 + lane15;

#define STAGE_G1(buf, kk0) do { \
    _Pragma("unroll") \
    for (int p = 0; p < 2; ++p) \
      GLOAD16(aBase + (size_t)(p * 32) * GK + (kk0), &As[buf][(p * 32 + wid * 8) * 64]); \
    _Pragma("unroll") \
    for (int p = 0; p < 4; ++p) \
      GLOAD16(bBase + (size_t)(p * 32) * GK + (kk0), &Bs[buf][(p * 32 + wid * 8) * 64]); \
    } while (0)

  STAGE_G1(0, 0);
  for (int t = 0; t < 15; ++t) {
    STAGE_G1((t + 1) & 1, (t + 1) * 64);
    WAIT_VMCNT6();
    __builtin_amdgcn_s_barrier();
    __builtin_amdgcn_sched_barrier(0);
    gemm_compute64(&As[t & 1][0], &Bs[t & 1][0], arow, brow, g, rx, acc);
    __builtin_amdgcn_sched_barrier(0);
    __builtin_amdgcn_s_barrier();
  }
  WAIT_VMCNT0();
  __builtin_amdgcn_s_barrier();
  gemm_compute64(&As[1][0], &Bs[1][0], arow, brow, g, rx, acc);

  #pragma unroll
  for (int fm = 0; fm < 2; ++fm)
    #pragma unroll
    for (int fn = 0; fn < 4; ++fn)
      #pragma unroll
      for (int i = 0; i < 4; ++i) {
        int gm = m0 + warp_m * 32 + fm * 16 + g * 4 + i;
        int gn = n0 + warp_n * 64 + fn * 16 + lane15;
        Fr[(size_t)gm * 1024 + gn] = f2bf(acc[fm][fn][i]);
      }
#undef STAGE_G1
}

// ---- GEMM2: out = gather(Ftb) * BT2^T, BM=64 (one batch/block), BN=128 ----
// n-slot s in [0,128): kk = bx*64 + (s&63) + (s>>6)*512  (ri = s>>6)
__global__ __launch_bounds__(256, 3) void gemm2(
    const ushort* __restrict__ Ftb, const ushort* __restrict__ Bt,
    float* __restrict__ out) {
  __shared__ __align__(16) ushort smem[2 * 64 * 64 + 2 * 128 * 64];
  ushort (*As)[64 * 64] = (ushort(*)[64 * 64])smem;
  ushort (*Bs)[128 * 64] = (ushort(*)[128 * 64])(smem + 2 * 64 * 64);
  float* CT = (float*)smem;                     // [128][65] after compute
  const int tid = threadIdx.x;
  const int wid = tid >> 6, lane = tid & 63;
  const int by = blockIdx.y, bx = blockIdx.x;   // by = batch b
  const int warp_m = wid >> 1, warp_n = wid & 1;

  floatx4 acc[2][4];
  #pragma unroll
  for (int i = 0; i < 2; ++i)
    #pragma unroll
    for (int j = 0; j < 4; ++j) acc[i][j] = (floatx4){0.f, 0.f, 0.f, 0.f};

  const int lr = lane >> 3, lc = lane & 7;
  const int swz = lc ^ lr;

  // A: frame rows f = p*32 + wid*8 + lr of batch by: Ftb[by*TLEN + f*256 + k]
  const ushort* aBase = Ftb + (size_t)by * TLEN + (wid * 8 + lr) * 256 + swz * 8;
  // B: permuted rows (both ri halves)
  const ushort* bB0 = Bt + (size_t)(bx * 64 + wid * 8 + lr) * GK + swz * 8;

  const int lane15 = lane & 15;
  const int g = lane >> 4;
  const int rx = lane & 7;
  const int arow = warp_m * 32 + lane15;
  const int brow = warp_n * 64 + lane15;

#define STAGE_G2(buf, kk0) do { \
    _Pragma("unroll") \
    for (int p = 0; p < 2; ++p) \
      GLOAD16(aBase + (size_t)(p * 32) * 256 + (kk0), &As[buf][(p * 32 + wid * 8) * 64]); \
    _Pragma("unroll") \
    for (int p = 0; p < 4; ++p) { \
      size_t boff = (size_t)((p & 1) * 32 + (p >> 1) * 512) * GK; \
      GLOAD16(bB0 + boff + (kk0), &Bs[buf][(((p >> 1) * 64 + (p & 1) * 32) + wid * 8) * 64]); \
    } } while (0)

  STAGE_G2(0, 0);
  for (int t = 0; t < 15; ++t) {
    STAGE_G2((t + 1) & 1, (t + 1) * 64);
    WAIT_VMCNT6();
    __builtin_amdgcn_s_barrier();
    __builtin_amdgcn_sched_barrier(0);
    gemm_compute64(&As[t & 1][0], &Bs[t & 1][0], arow, brow, g, rx, acc);
    __builtin_amdgcn_sched_barrier(0);
    __builtin_amdgcn_s_barrier();
  }
  WAIT_VMCNT0();
  __builtin_amdgcn_s_barrier();
  gemm_compute64(&As[1][0], &Bs[1][0], arow, brow, g, rx, acc);

  // epilogue: acc -> CT[s][f] (padded 65), then coalesced 512B row writes
  __syncthreads();
  #pragma unroll
  for (int fm = 0; fm < 2; ++fm)
    #pragma unroll
    for (int fn = 0; fn < 4; ++fn)
      #pragma unroll
      for (int i = 0; i < 4; ++i) {
        int s    = warp_n * 64 + fn * 16 + lane15;
        int fcol = warp_m * 32 + fm * 16 + g * 4 + i;
        CT[s * 65 + fcol] = acc[fm][fn][i];
      }
  __syncthreads();
  // out[((by*512 + bx*64 + r))*128 + q*4 ...]: r k-local, q float4-quad
  #pragma unroll
  for (int e = 0; e < 8; ++e) {
    int it = tid + e * 256;
    int r = it >> 5, q = it & 31;
    float4 v;
    v.x = CT[r * 65 + 2 * q];             // f=2q,  ri=0
    v.y = CT[(64 + r) * 65 + 2 * q];      // f=2q,  ri=1
    v.z = CT[r * 65 + 2 * q + 1];         // f=2q+1,ri=0
    v.w = CT[(64 + r) * 65 + 2 * q + 1];  // f=2q+1,ri=1
    *(float4*)&out[((size_t)(by * 512 + bx * 64 + r)) * 128 + q * 4] = v;
  }
#undef STAGE_G2
}

// ---------------- fused overlap-add + filtfilt -> bf16 signal ----------------
#define SWZ(r) ((r) ^ (((r) >> 6) & 31))

static __device__ __forceinline__ float oa_sample(const ushort* __restrict__ frb,
                                                  int tau) {
  int fhi = tau >> 8;
  int flo = fhi - 3; if (flo < 0) flo = 0;
  if (fhi > 63) fhi = 63;
  float sum = 0.f;
  for (int f = flo; f <= fhi; ++f) {
    int off = tau - (f << 8);
    if (off < NW) sum += bf2f(frb[(size_t)f * 1024 + off]);
  }
  return sum;
}

#define IIR_STEP(x, y)                                   \
  float y = fmaf(cf.b0, (x), z0);                        \
  z0 = fmaf(-cf.a1, y, fmaf(cf.b1, (x), z1));            \
  z1 = fmaf(-cf.a2, y, fmaf(cf.b2, (x), z2));            \
  z2 = fmaf(-cf.a3, y, fmaf(cf.b3, (x), z3));            \
  z3 = fmaf(-cf.a4, y, fmaf(cf.b4, (x), z4));            \
  z4 = fmaf(-cf.a5, y, cf.b5 * (x));

__global__ __launch_bounds__(256) void oa_iir(const ushort* __restrict__ Fr,
                                              ushort* __restrict__ Ftb,
                                              IirCoef cf) {
  __shared__ float bufX[SPAN];   // xe, later y2
  __shared__ float bufY[SPAN];   // y1
  const int blk = blockIdx.x;
  const int b = blk >> 2, sp = blk & 3;
  const int lo = sp * BS;
  const int hi = (lo + BS < TLEN) ? lo + BS : TLEN;     // filt range [lo,hi)
  const int F0 = (sp == 0) ? 0 : lo + PADL;             // fwd output xe-range
  int F1 = hi + PADL + 128; if (F1 > LXLEN) F1 = LXLEN;
  const int XB = (sp == 0) ? 0 : F0 - 64;               // xe LDS base
  const int xspan = F1 - XB;                            // <= SPAN
  const ushort* frb = Fr + (size_t)(b * 64) * 1024;

  // phase 1: xe -> bufX (reflect-pad over overlap-add, computed on the fly)
  for (int rel = threadIdx.x; rel < xspan; rel += 256) {
    int p = XB + rel;
    float v;
    if (p < PADL)
      v = 2.f * oa_sample(frb, 0) - oa_sample(frb, PADL - p);
    else if (p < PADL + TLEN)
      v = oa_sample(frb, p - PADL);
    else {
      int j = p - (PADL + TLEN);
      v = 2.f * oa_sample(frb, TLEN - 1) - oa_sample(frb, TLEN - 2 - j);
    }
    bufX[SWZ(rel)] = v;
  }
  __syncthreads();

  // phase 2: forward IIR chunks (64 warm + 64 live), bufX -> bufY
  {
    int nch = (F1 - F0 + 63) >> 6;
    int c = threadIdx.x;
    if (c < nch) {
      int os = F0 + (c << 6);
      int oe = os + 64; if (oe > F1) oe = F1;
      float z0, z1, z2, z3, z4;
      int i;
      if (sp == 0 && c == 0) {
        float x0 = bufX[SWZ(0)];
        z0 = cf.zi0 * x0; z1 = cf.zi1 * x0; z2 = cf.zi2 * x0;
        z3 = cf.zi3 * x0; z4 = cf.zi4 * x0;
        i = 0;
      } else {
        z0 = z1 = z2 = z3 = z4 = 0.f;
        i = os - 64;
        #pragma unroll 4
        for (; i < os; ++i) { float x = bufX[SWZ(i - XB)]; IIR_STEP(x, y); (void)y; }
      }
      #pragma unroll 4
      for (; i < oe; ++i) {
        float x = bufX[SWZ(i - XB)];
        IIR_STEP(x, y);
        bufY[SWZ(i - XB)] = y;
      }
    }
  }
  __syncthreads();

  // phase 3: backward IIR chunks (absolute 64-aligned reversed grid), bufY -> bufX
  {
    const int R0 = TLEN + PADL - hi;          // owned reversed range [R0, R1)
    const int R1 = LXLEN - lo - PADL;
    int k_lo = R0 >> 6, k_hi = (R1 - 1) >> 6;
    int k = k_lo + threadIdx.x;
    if (k <= k_hi) {
      int rs = k << 6;
      int re = rs + 64; if (re > R1) re = R1;
      float z0, z1, z2, z3, z4;
      int i;
      if (k == 0) {
        float x0 = bufY[SWZ(LXLEN - 1 - XB)];
        z0 = cf.zi0 * x0; z1 = cf.zi1 * x0; z2 = cf.zi2 * x0;
        z3 = cf.zi3 * x0; z4 = cf.zi4 * x0;
        i = 0;
      } else {
        z0 = z1 = z2 = z3 = z4 = 0.f;
        i = rs - 64;
        #pragma unroll 4
        for (; i < rs; ++i) { float x = bufY[SWZ(LXLEN - 1 - i - XB)]; IIR_STEP(x, y); (void)y; }
      }
      #pragma unroll 4
      for (; i < re; ++i) {
        float x = bufY[SWZ(LXLEN - 1 - i - XB)];
        IIR_STEP(x, y);
        if (i >= R0) bufX[SWZ(LXLEN - 1 - i - XB)] = y;
      }
    }
  }
  __syncthreads();

  // phase 4: coalesced bf16 write of owned filt range
  for (int t = lo + threadIdx.x; t < hi; t += 256)
    Ftb[(size_t)b * TLEN + t] = f2bf(bufX[SWZ(t + PADL - XB)]);
  // zero-pad tail so gemm2's K-padding reads stay finite
  if (b == NB - 1 && sp == 3)
    for (int t = threadIdx.x; t < 1024; t += 256)
      Ftb[(size_t)NB * TLEN + t] = 0;
}

// ---------------- host: butter(5,0.5) + lfilter_zi ----------------
static void solve5(double M[5][5], double v[5], double outv[5]) {
  for (int col = 0; col < 5; ++col) {
    int piv = col;
    for (int r = col + 1; r < 5; ++r)
      if (std::fabs(M[r][col]) > std::fabs(M[piv][col])) piv = r;
    if (piv != col) {
      for (int c = 0; c < 5; ++c) std::swap(M[col][c], M[piv][c]);
      std::swap(v[col], v[piv]);
    }
    double d = M[col][col];
    for (int r = col + 1; r < 5; ++r) {
      double f = M[r][col] / d;
      for (int c = col; c < 5; ++c) M[r][c] -= f * M[col][c];
      v[r] -= f * v[col];
    }
  }
  for (int r = 4; r >= 0; --r) {
    double s = v[r];
    for (int c = r + 1; c < 5; ++c) s -= M[r][c] * outv[c];
    outv[r] = s / M[r][r];
  }
}

static IirCoef make_coef() {
  const double PI = 3.14159265358979323846;
  std::complex<double> p[5];
  for (int i = 0; i < 5; ++i) {
    double m = -4.0 + 2.0 * i;
    p[i] = -std::exp(std::complex<double>(0.0, PI * m / 10.0));
  }
  double fs = 2.0;
  double warped = 2.0 * fs * std::tan(PI * 0.5 / fs);
  for (int i = 0; i < 5; ++i) p[i] *= warped;
  double kgain = std::pow(warped, 5.0);
  double fs2 = 2.0 * fs;
  std::complex<double> pd[5], prod(1.0, 0.0);
  for (int i = 0; i < 5; ++i) {
    pd[i] = (fs2 + p[i]) / (fs2 - p[i]);
    prod *= (fs2 - p[i]);
  }
  double kd = kgain * std::real(1.0 / prod);
  double b[6] = {kd, 5 * kd, 10 * kd, 10 * kd, 5 * kd, kd};
  std::complex<double> c[6] = {{1,0},{0,0},{0,0},{0,0},{0,0},{0,0}};
  for (int i = 0; i < 5; ++i)
    for (int j = i + 1; j >= 1; --j)
      c[j] -= pd[i] * c[j - 1];
  double a[6]; for (int i = 0; i < 6; ++i) a[i] = c[i].real();
  double M[5][5], v[5];
  for (int r = 0; r < 5; ++r)
    for (int cc = 0; cc < 5; ++cc) {
      double Af = 0.0;
      if (cc == 0) Af = -a[r + 1];
      if (cc == r + 1) Af = 1.0;
      M[r][cc] = (r == cc ? 1.0 : 0.0) - Af;
    }
  for (int r = 0; r < 5; ++r) v[r] = b[r + 1] - a[r + 1] * b[0];
  double zi[5];
  solve5(M, v, zi);
  IirCoef cf;
  cf.b0 = (float)b[0]; cf.b1 = (float)b[1]; cf.b2 = (float)b[2];
  cf.b3 = (float)b[3]; cf.b4 = (float)b[4]; cf.b5 = (float)b[5];
  cf.a1 = (float)a[1]; cf.a2 = (float)a[2]; cf.a3 = (float)a[3];
  cf.a4 = (float)a[4]; cf.a5 = (float)a[5];
  cf.zi0 = (float)zi[0]; cf.zi1 = (float)zi[1]; cf.zi2 = (float)zi[2];
  cf.zi3 = (float)zi[3]; cf.zi4 = (float)zi[4];
  return cf;
}

extern "C" void kernel_launch(void* const* d_in, const int* in_sizes, int n_in,
                              void* d_out, int out_size, void* d_ws, size_t ws_size,
                              hipStream_t stream) {
  const float* x = (const float*)d_in[0];
  float* out = (float*)d_out;

  // workspace layout (bf16 everywhere except out)
  ushort* BT1 = (ushort*)d_ws;                   // 1024*1024
  ushort* BT2 = BT1 + 1024 * 1024;               // 1024*1024
  ushort* A1  = BT2 + 1024 * 1024;               // 4096*1024
  ushort* Ftb = A1 + (size_t)NFRAMES * 1024;     // NB*TLEN + 1024
  ushort* Fr  = Ftb + (size_t)NB * TLEN + 1024;  // 4096*1024 (bf16 frames)
  size_t need = (size_t)((char*)(Fr + (size_t)NFRAMES * 1024) - (char*)d_ws);
  if (ws_size < need) return;

  IirCoef cf = make_coef();

  prep<<<9216, 256, 0, stream>>>(x, BT1, BT2, A1);
  gemm1<<<dim3(8, 64), 256, 0, stream>>>(A1, BT1, Fr);
  oa_iir<<<NB * 4, 256, 0, stream>>>(Fr, Ftb, cf);
  gemm2<<<dim3(8, 64), 256, 0, stream>>>(Ftb, BT2, out);
}

// Round 9
// 68.222 us; speedup vs baseline: 1.1983x; 1.1983x over previous
//
#include <hip/hip_runtime.h>
#include <cmath>
#include <complex>
#include <algorithm>

#define NW      1022
#define NB      64
#define TLEN    17150   /* HOP*(F-1)+W */
#define PADL    18
#define LXLEN   17186   /* TLEN + 2*PADL */
#define NFRAMES 4096    /* NB*64 */
#define GK      1024    /* padded K for both GEMMs */
#define NSPLIT  8
#define BS      2144    /* samples per oa_iir split */
#define SPAN    2336    /* LDS floats per buffer in oa_iir */

typedef __attribute__((ext_vector_type(8))) short short8;
typedef __attribute__((ext_vector_type(4))) short short4v;
typedef __attribute__((ext_vector_type(4))) float floatx4;

struct IirCoef {
  float b0,b1,b2,b3,b4,b5;
  float a1,a2,a3,a4,a5;
  float zi0,zi1,zi2,zi3,zi4;
};

static __device__ __forceinline__ ushort f2bf(float f) {
  uint32_t u = __builtin_bit_cast(uint32_t, f);
  uint32_t r = (u + 0x7FFFu + ((u >> 16) & 1u)) >> 16;   // RNE
  return (ushort)r;
}
static __device__ __forceinline__ float bf2f(ushort u) {
  return __builtin_bit_cast(float, (uint32_t)u << 16);
}

// fp32-exact (k*t) mod 1022 (k<=511, t<=1021: k*t < 2^24), then radians
static __device__ __forceinline__ float phase_mod(int k, int t) {
  const float TPN = 6.2831853071795864769f / 1022.f;
  float kt = (float)(k * t);
  float q = floorf(kt * (1.0f / 1022.0f));
  float r = kt - q * 1022.0f;
  if (r < 0.f) r += 1022.f;
  if (r >= 1022.f) r -= 1022.f;
  return r * TPN;
}

// ---------------- prep: BT1 (vec4) | A1-transpose ----------------
// blocks [0,1024): BT1[t][kk] (irfft basis * syn), 4 kk per thread
// blocks [1024,2048): A1 transpose tiles
__global__ __launch_bounds__(256) void prep(const float* __restrict__ x,
                                            ushort* __restrict__ BT1,
                                            ushort* __restrict__ A1) {
  __shared__ float tile[32][129];
  const float TPN = 6.2831853071795864769f / 1022.f;
  int bid = blockIdx.x;
  if (bid < 1024) {
    int idx4 = (bid * 256 + threadIdx.x) * 4;   // 4 consecutive kk, same t
    int t = idx4 >> 10, kk0 = idx4 & 1023;
    short4v v = (short4v){0, 0, 0, 0};
    if (t < NW) {
      float fw = 0.5f - 0.5f * __cosf((float)t * TPN);
      float den = 0.f;
      int tm = t & 255;
      #pragma unroll
      for (int j = 0; j < 4; ++j) {
        int u = tm + (j << 8);
        if (u < NW) { float w = 0.5f - 0.5f * __cosf((float)u * TPN); den += w * w; }
      }
      float syn = fw / den;
      #pragma unroll
      for (int e = 0; e < 4; ++e) {
        int kk = kk0 + e, k = kk & 511;
        float arg = phase_mod(k, t);
        float scale = (k == 0 || k == 511) ? 1.f : 2.f;
        float val;
        if (kk < 512) val = __cosf(arg) * scale * (1.f / 1022.f) * syn;
        else          val = (k == 0 || k == 511) ? 0.f
                            : -__sinf(arg) * scale * (1.f / 1022.f) * syn;
        v[e] = (short)f2bf(val);
      }
    }
    *(short4v*)&BT1[idx4] = v;
  } else {
    int tb = bid - 1024;
    int b  = tb >> 4;
    int k0 = (tb & 15) << 5;
    int tid = threadIdx.x;
    #pragma unroll
    for (int e = 0; e < 16; ++e) {
      int lin = tid + e * 256;
      int i = lin >> 7, c = lin & 127;
      tile[i][c] = x[(b * 512 + k0 + i) * 128 + c];
    }
    __syncthreads();
    #pragma unroll
    for (int e = 0; e < 16; ++e) {
      int lin = tid + e * 256;
      int c = lin >> 5, i = lin & 31;
      int f = c >> 1, ri = c & 1;
      A1[(b * 64 + f) * 1024 + ri * 512 + k0 + i] = f2bf(tile[i][c]);
    }
  }
}

// ---------------- shared GEMM pieces ----------------
#define GLOAD16(gsrc, ldst) \
  __builtin_amdgcn_global_load_lds( \
      (const __attribute__((address_space(1))) void*)(gsrc), \
      (__attribute__((address_space(3))) void*)(ldst), 16, 0, 0)

#define WAIT_VMCNT6()  __builtin_amdgcn_s_waitcnt(0xF76)  /* vmcnt(6) */
#define WAIT_VMCNT0()  __builtin_amdgcn_s_waitcnt(0xF70)  /* vmcnt(0) */

// wave-tile 32x64: acc[2][4]
static __device__ __forceinline__ void gemm_compute64(
    const ushort* as, const ushort* bs, int arow, int brow, int g, int rx,
    floatx4 (&acc)[2][4]) {
  #pragma unroll
  for (int ks = 0; ks < 2; ++ks) {
    short8 af[2], bfr[4];
    const int chunk = ((ks << 2) + g) ^ rx;
    #pragma unroll
    for (int fm = 0; fm < 2; ++fm)
      af[fm] = *(const short8*)(as + (arow + fm * 16) * 64 + chunk * 8);
    #pragma unroll
    for (int fn = 0; fn < 4; ++fn)
      bfr[fn] = *(const short8*)(bs + (brow + fn * 16) * 64 + chunk * 8);
    #pragma unroll
    for (int fm = 0; fm < 2; ++fm)
      #pragma unroll
      for (int fn = 0; fn < 4; ++fn)
        acc[fm][fn] = __builtin_amdgcn_mfma_f32_16x16x32_bf16(
            af[fm], bfr[fn], acc[fm][fn], 0, 0, 0);
  }
}

// ---- GEMM1: frames(bf16)[4096,1024] = A1 * BT1^T, XCD-swizzled; ----
// ---- plus rider blocks (by>=64, 1024 blocks) generating BT2 (vec4) ----
__global__ __launch_bounds__(256, 3) void gemm1(
    const ushort* __restrict__ A, const ushort* __restrict__ Bt,
    ushort* __restrict__ Fr, ushort* __restrict__ BT2) {
  __shared__ __align__(16) ushort As[2][64 * 64];
  __shared__ __align__(16) ushort Bs[2][128 * 64];
  const float TPN = 6.2831853071795864769f / 1022.f;

  if (blockIdx.y >= 64) {            // BT2 rider: 1024 blocks, 1M elems vec4
    int bid = (blockIdx.y - 64) * 8 + blockIdx.x;      // 0..1023
    int idx4 = (bid * 256 + threadIdx.x) * 4;          // 4 consecutive t, same kk
    int kk = idx4 >> 10, t0 = idx4 & 1023;
    int k = kk & 511;
    short4v v = (short4v){0, 0, 0, 0};
    #pragma unroll
    for (int e = 0; e < 4; ++e) {
      int t = t0 + e;
      if (t < NW) {
        float fw = 0.5f - 0.5f * __cosf((float)t * TPN);
        float arg = phase_mod(k, t);
        float val = (kk < 512) ? fw * __cosf(arg) : -fw * __sinf(arg);
        v[e] = (short)f2bf(val);
      }
    }
    *(short4v*)&BT2[idx4] = v;
    return;
  }

  // XCD-aware remap: cluster 8 m-panels per XCD so A stays L2-resident.
  const int L = blockIdx.x + 8 * blockIdx.y;   // 0..511
  const int xcd = L & 7, j = L >> 3;
  const int by_n = xcd * 8 + (j & 7);          // 0..63
  const int bx_n = j >> 3;                     // 0..7

  const int tid = threadIdx.x;
  const int wid = tid >> 6, lane = tid & 63;
  const int m0 = by_n * 64, n0 = bx_n * 128;
  const int warp_m = wid >> 1, warp_n = wid & 1;

  floatx4 acc[2][4];
  #pragma unroll
  for (int i = 0; i < 2; ++i)
    #pragma unroll
    for (int jj = 0; jj < 4; ++jj) acc[i][jj] = (floatx4){0.f, 0.f, 0.f, 0.f};

  const int lr = lane >> 3, lc = lane & 7;
  const int swz = lc ^ lr;
  const ushort* aBase = A  + (size_t)(m0 + wid * 8 + lr) * GK + swz * 8;
  const ushort* bBase = Bt + (size_t)(n0 + wid * 8 + lr) * GK + swz * 8;

  const int lane15 = lane & 15;
  const int g = lane >> 4;
  const int rx = lane & 7;
  const int arow = warp_m * 32 + lane15;
  const int brow = warp_n * 64 + lane15;

#define STAGE_G1(buf, kk0) do { \
    _Pragma("unroll") \
    for (int p = 0; p < 2; ++p) \
      GLOAD16(aBase + (size_t)(p * 32) * GK + (kk0), &As[buf][(p * 32 + wid * 8) * 64]); \
    _Pragma("unroll") \
    for (int p = 0; p < 4; ++p) \
      GLOAD16(bBase + (size_t)(p * 32) * GK + (kk0), &Bs[buf][(p * 32 + wid * 8) * 64]); \
    } while (0)

  STAGE_G1(0, 0);
  for (int t = 0; t < 15; ++t) {
    STAGE_G1((t + 1) & 1, (t + 1) * 64);
    WAIT_VMCNT6();
    __builtin_amdgcn_s_barrier();
    __builtin_amdgcn_sched_barrier(0);
    gemm_compute64(&As[t & 1][0], &Bs[t & 1][0], arow, brow, g, rx, acc);
    __builtin_amdgcn_sched_barrier(0);
    __builtin_amdgcn_s_barrier();
  }
  WAIT_VMCNT0();
  __builtin_amdgcn_s_barrier();
  gemm_compute64(&As[1][0], &Bs[1][0], arow, brow, g, rx, acc);

  #pragma unroll
  for (int fm = 0; fm < 2; ++fm)
    #pragma unroll
    for (int fn = 0; fn < 4; ++fn)
      #pragma unroll
      for (int i = 0; i < 4; ++i) {
        int gm = m0 + warp_m * 32 + fm * 16 + g * 4 + i;
        int gn = n0 + warp_n * 64 + fn * 16 + lane15;
        Fr[(size_t)gm * 1024 + gn] = f2bf(acc[fm][fn][i]);
      }
#undef STAGE_G1
}

// ---- GEMM2: out = gather(Ftb) * BT2^T, BM=64 (one batch/block), BN=128 ----
__global__ __launch_bounds__(256, 3) void gemm2(
    const ushort* __restrict__ Ftb, const ushort* __restrict__ Bt,
    float* __restrict__ out) {
  __shared__ __align__(16) ushort smem[2 * 64 * 64 + 2 * 128 * 64];
  ushort (*As)[64 * 64] = (ushort(*)[64 * 64])smem;
  ushort (*Bs)[128 * 64] = (ushort(*)[128 * 64])(smem + 2 * 64 * 64);
  float* CT = (float*)smem;                     // [128][65] after compute
  const int tid = threadIdx.x;
  const int wid = tid >> 6, lane = tid & 63;
  const int by = blockIdx.y, bx = blockIdx.x;   // by = batch b
  const int warp_m = wid >> 1, warp_n = wid & 1;

  floatx4 acc[2][4];
  #pragma unroll
  for (int i = 0; i < 2; ++i)
    #pragma unroll
    for (int j = 0; j < 4; ++j) acc[i][j] = (floatx4){0.f, 0.f, 0.f, 0.f};

  const int lr = lane >> 3, lc = lane & 7;
  const int swz = lc ^ lr;

  const ushort* aBase = Ftb + (size_t)by * TLEN + (wid * 8 + lr) * 256 + swz * 8;
  const ushort* bB0 = Bt + (size_t)(bx * 64 + wid * 8 + lr) * GK + swz * 8;

  const int lane15 = lane & 15;
  const int g = lane >> 4;
  const int rx = lane & 7;
  const int arow = warp_m * 32 + lane15;
  const int brow = warp_n * 64 + lane15;

#define STAGE_G2(buf, kk0) do { \
    _Pragma("unroll") \
    for (int p = 0; p < 2; ++p) \
      GLOAD16(aBase + (size_t)(p * 32) * 256 + (kk0), &As[buf][(p * 32 + wid * 8) * 64]); \
    _Pragma("unroll") \
    for (int p = 0; p < 4; ++p) { \
      size_t boff = (size_t)((p & 1) * 32 + (p >> 1) * 512) * GK; \
      GLOAD16(bB0 + boff + (kk0), &Bs[buf][(((p >> 1) * 64 + (p & 1) * 32) + wid * 8) * 64]); \
    } } while (0)

  STAGE_G2(0, 0);
  for (int t = 0; t < 15; ++t) {
    STAGE_G2((t + 1) & 1, (t + 1) * 64);
    WAIT_VMCNT6();
    __builtin_amdgcn_s_barrier();
    __builtin_amdgcn_sched_barrier(0);
    gemm_compute64(&As[t & 1][0], &Bs[t & 1][0], arow, brow, g, rx, acc);
    __builtin_amdgcn_sched_barrier(0);
    __builtin_amdgcn_s_barrier();
  }
  WAIT_VMCNT0();
  __builtin_amdgcn_s_barrier();
  gemm_compute64(&As[1][0], &Bs[1][0], arow, brow, g, rx, acc);

  __syncthreads();
  #pragma unroll
  for (int fm = 0; fm < 2; ++fm)
    #pragma unroll
    for (int fn = 0; fn < 4; ++fn)
      #pragma unroll
      for (int i = 0; i < 4; ++i) {
        int s    = warp_n * 64 + fn * 16 + lane15;
        int fcol = warp_m * 32 + fm * 16 + g * 4 + i;
        CT[s * 65 + fcol] = acc[fm][fn][i];
      }
  __syncthreads();
  #pragma unroll
  for (int e = 0; e < 8; ++e) {
    int it = tid + e * 256;
    int r = it >> 5, q = it & 31;
    float4 v;
    v.x = CT[r * 65 + 2 * q];
    v.y = CT[(64 + r) * 65 + 2 * q];
    v.z = CT[r * 65 + 2 * q + 1];
    v.w = CT[(64 + r) * 65 + 2 * q + 1];
    *(float4*)&out[((size_t)(by * 512 + bx * 64 + r)) * 128 + q * 4] = v;
  }
#undef STAGE_G2
}

// ---------------- fused overlap-add + filtfilt -> bf16 signal ----------------
#define SWZ(r) ((r) ^ (((r) >> 6) & 31))

static __device__ __forceinline__ float oa_sample(const ushort* __restrict__ frb,
                                                  int tau) {
  int fhi = tau >> 8;
  int flo = fhi - 3; if (flo < 0) flo = 0;
  if (fhi > 63) fhi = 63;
  float sum = 0.f;
  for (int f = flo; f <= fhi; ++f) {
    int off = tau - (f << 8);
    if (off < NW) sum += bf2f(frb[(size_t)f * 1024 + off]);
  }
  return sum;
}

#define IIR_STEP(x, y)                                   \
  float y = fmaf(cf.b0, (x), z0);                        \
  z0 = fmaf(-cf.a1, y, fmaf(cf.b1, (x), z1));            \
  z1 = fmaf(-cf.a2, y, fmaf(cf.b2, (x), z2));            \
  z2 = fmaf(-cf.a3, y, fmaf(cf.b3, (x), z3));            \
  z3 = fmaf(-cf.a4, y, fmaf(cf.b4, (x), z4));            \
  z4 = fmaf(-cf.a5, y, cf.b5 * (x));

__global__ __launch_bounds__(256) void oa_iir(const ushort* __restrict__ Fr,
                                              ushort* __restrict__ Ftb,
                                              IirCoef cf) {
  __shared__ float bufX[SPAN];   // xe, later y2
  __shared__ float bufY[SPAN];   // y1
  const int blk = blockIdx.x;
  const int b = blk >> 3, sp = blk & 7;
  const int lo = sp * BS;
  const int hi = (lo + BS < TLEN) ? lo + BS : TLEN;     // filt range [lo,hi)
  const int F0 = (sp == 0) ? 0 : lo + PADL;             // fwd output xe-range
  int F1 = hi + PADL + 128; if (F1 > LXLEN) F1 = LXLEN;
  const int XB = (sp == 0) ? 0 : F0 - 64;               // xe LDS base
  const int xspan = F1 - XB;                            // <= SPAN
  const ushort* frb = Fr + (size_t)(b * 64) * 1024;

  // phase 1: xe -> bufX (reflect-pad over overlap-add, computed on the fly)
  for (int rel = threadIdx.x; rel < xspan; rel += 256) {
    int p = XB + rel;
    float v;
    if (p < PADL)
      v = 2.f * oa_sample(frb, 0) - oa_sample(frb, PADL - p);
    else if (p < PADL + TLEN)
      v = oa_sample(frb, p - PADL);
    else {
      int j = p - (PADL + TLEN);
      v = 2.f * oa_sample(frb, TLEN - 1) - oa_sample(frb, TLEN - 2 - j);
    }
    bufX[SWZ(rel)] = v;
  }
  __syncthreads();

  // phase 2: forward IIR chunks (64 warm + 64 live), bufX -> bufY
  {
    int nch = (F1 - F0 + 63) >> 6;
    int c = threadIdx.x;
    if (c < nch) {
      int os = F0 + (c << 6);
      int oe = os + 64; if (oe > F1) oe = F1;
      float z0, z1, z2, z3, z4;
      int i;
      if (sp == 0 && c == 0) {
        float x0 = bufX[SWZ(0)];
        z0 = cf.zi0 * x0; z1 = cf.zi1 * x0; z2 = cf.zi2 * x0;
        z3 = cf.zi3 * x0; z4 = cf.zi4 * x0;
        i = 0;
      } else {
        z0 = z1 = z2 = z3 = z4 = 0.f;
        i = os - 64;
        #pragma unroll 4
        for (; i < os; ++i) { float x = bufX[SWZ(i - XB)]; IIR_STEP(x, y); (void)y; }
      }
      #pragma unroll 4
      for (; i < oe; ++i) {
        float x = bufX[SWZ(i - XB)];
        IIR_STEP(x, y);
        bufY[SWZ(i - XB)] = y;
      }
    }
  }
  __syncthreads();

  // phase 3: backward IIR chunks (absolute 64-aligned reversed grid), bufY -> bufX
  {
    const int R0 = TLEN + PADL - hi;          // owned reversed range [R0, R1)
    const int R1 = LXLEN - lo - PADL;
    int k_lo = R0 >> 6, k_hi = (R1 - 1) >> 6;
    int k = k_lo + threadIdx.x;
    if (k <= k_hi) {
      int rs = k << 6;
      int re = rs + 64; if (re > R1) re = R1;
      float z0, z1, z2, z3, z4;
      int i;
      if (k == 0) {
        float x0 = bufY[SWZ(LXLEN - 1 - XB)];
        z0 = cf.zi0 * x0; z1 = cf.zi1 * x0; z2 = cf.zi2 * x0;
        z3 = cf.zi3 * x0; z4 = cf.zi4 * x0;
        i = 0;
      } else {
        z0 = z1 = z2 = z3 = z4 = 0.f;
        i = rs - 64;
        #pragma unroll 4
        for (; i < rs; ++i) { float x = bufY[SWZ(LXLEN - 1 - i - XB)]; IIR_STEP(x, y); (void)y; }
      }
      #pragma unroll 4
      for (; i < re; ++i) {
        float x = bufY[SWZ(LXLEN - 1 - i - XB)];
        IIR_STEP(x, y);
        if (i >= R0) bufX[SWZ(LXLEN - 1 - i - XB)] = y;
      }
    }
  }
  __syncthreads();

  // phase 4: coalesced bf16 write of owned filt range
  for (int t = lo + threadIdx.x; t < hi; t += 256)
    Ftb[(size_t)b * TLEN + t] = f2bf(bufX[SWZ(t + PADL - XB)]);
  // zero-pad tail so gemm2's K-padding reads stay finite
  if (b == NB - 1 && sp == NSPLIT - 1)
    for (int t = threadIdx.x; t < 1024; t += 256)
      Ftb[(size_t)NB * TLEN + t] = 0;
}

// ---------------- host: butter(5,0.5) + lfilter_zi ----------------
static void solve5(double M[5][5], double v[5], double outv[5]) {
  for (int col = 0; col < 5; ++col) {
    int piv = col;
    for (int r = col + 1; r < 5; ++r)
      if (std::fabs(M[r][col]) > std::fabs(M[piv][col])) piv = r;
    if (piv != col) {
      for (int c = 0; c < 5; ++c) std::swap(M[col][c], M[piv][c]);
      std::swap(v[col], v[piv]);
    }
    double d = M[col][col];
    for (int r = col + 1; r < 5; ++r) {
      double f = M[r][col] / d;
      for (int c = col; c < 5; ++c) M[r][c] -= f * M[col][c];
      v[r] -= f * v[col];
    }
  }
  for (int r = 4; r >= 0; --r) {
    double s = v[r];
    for (int c = r + 1; c < 5; ++c) s -= M[r][c] * outv[c];
    outv[r] = s / M[r][r];
  }
}

static IirCoef make_coef() {
  const double PI = 3.14159265358979323846;
  std::complex<double> p[5];
  for (int i = 0; i < 5; ++i) {
    double m = -4.0 + 2.0 * i;
    p[i] = -std::exp(std::complex<double>(0.0, PI * m / 10.0));
  }
  double fs = 2.0;
  double warped = 2.0 * fs * std::tan(PI * 0.5 / fs);
  for (int i = 0; i < 5; ++i) p[i] *= warped;
  double kgain = std::pow(warped, 5.0);
  double fs2 = 2.0 * fs;
  std::complex<double> pd[5], prod(1.0, 0.0);
  for (int i = 0; i < 5; ++i) {
    pd[i] = (fs2 + p[i]) / (fs2 - p[i]);
    prod *= (fs2 - p[i]);
  }
  double kd = kgain * std::real(1.0 / prod);
  double b[6] = {kd, 5 * kd, 10 * kd, 10 * kd, 5 * kd, kd};
  std::complex<double> c[6] = {{1,0},{0,0},{0,0},{0,0},{0,0},{0,0}};
  for (int i = 0; i < 5; ++i)
    for (int j = i + 1; j >= 1; --j)
      c[j] -= pd[i] * c[j - 1];
  double a[6]; for (int i = 0; i < 6; ++i) a[i] = c[i].real();
  double M[5][5], v[5];
  for (int r = 0; r < 5; ++r)
    for (int cc = 0; cc < 5; ++cc) {
      double Af = 0.0;
      if (cc == 0) Af = -a[r + 1];
      if (cc == r + 1) Af = 1.0;
      M[r][cc] = (r == cc ? 1.0 : 0.0) - Af;
    }
  for (int r = 0; r < 5; ++r) v[r] = b[r + 1] - a[r + 1] * b[0];
  double zi[5];
  solve5(M, v, zi);
  IirCoef cf;
  cf.b0 = (float)b[0]; cf.b1 = (float)b[1]; cf.b2 = (float)b[2];
  cf.b3 = (float)b[3]; cf.b4 = (float)b[4]; cf.b5 = (float)b[5];
  cf.a1 = (float)a[1]; cf.a2 = (float)a[2]; cf.a3 = (float)a[3];
  cf.a4 = (float)a[4]; cf.a5 = (float)a[5];
  cf.zi0 = (float)zi[0]; cf.zi1 = (float)zi[1]; cf.zi2 = (float)zi[2];
  cf.zi3 = (float)zi[3]; cf.zi4 = (float)zi[4];
  return cf;
}

extern "C" void kernel_launch(void* const* d_in, const int* in_sizes, int n_in,
                              void* d_out, int out_size, void* d_ws, size_t ws_size,
                              hipStream_t stream) {
  const float* x = (const float*)d_in[0];
  float* out = (float*)d_out;

  // workspace layout (bf16 everywhere except out)
  ushort* BT1 = (ushort*)d_ws;                   // 1024*1024
  ushort* BT2 = BT1 + 1024 * 1024;               // 1024*1024
  ushort* A1  = BT2 + 1024 * 1024;               // 4096*1024
  ushort* Ftb = A1 + (size_t)NFRAMES * 1024;     // NB*TLEN + 1024
  ushort* Fr  = Ftb + (size_t)NB * TLEN + 1024;  // 4096*1024 (bf16 frames)
  size_t need = (size_t)((char*)(Fr + (size_t)NFRAMES * 1024) - (char*)d_ws);
  if (ws_size < need) return;

  IirCoef cf = make_coef();

  prep<<<2048, 256, 0, stream>>>(x, BT1, A1);
  gemm1<<<dim3(8, 192), 256, 0, stream>>>(A1, BT1, Fr, BT2);
  oa_iir<<<NB * NSPLIT, 256, 0, stream>>>(Fr, Ftb, cf);
  gemm2<<<dim3(8, 64), 256, 0, stream>>>(Ftb, BT2, out);
}

// Round 10
// 67.432 us; speedup vs baseline: 1.2123x; 1.0117x over previous
//
#include <hip/hip_runtime.h>
#include <cmath>
#include <complex>
#include <algorithm>

#define NW      1022
#define NB      64
#define TLEN    17150   /* HOP*(F-1)+W */
#define PADL    18
#define LXLEN   17186   /* TLEN + 2*PADL */
#define NFRAMES 4096    /* NB*64 */
#define GK      1024    /* padded K for both GEMMs */
#define NSPLIT  8
#define BS      2144    /* samples per oa_iir split */
#define SPAN    2336    /* LDS floats per buffer in oa_iir */

typedef __attribute__((ext_vector_type(8))) short short8;
typedef __attribute__((ext_vector_type(4))) short short4v;
typedef __attribute__((ext_vector_type(4))) float floatx4;

struct IirCoef {
  float b0,b1,b2,b3,b4,b5;
  float a1,a2,a3,a4,a5;
  float zi0,zi1,zi2,zi3,zi4;
};

static __device__ __forceinline__ ushort f2bf(float f) {
  uint32_t u = __builtin_bit_cast(uint32_t, f);
  uint32_t r = (u + 0x7FFFu + ((u >> 16) & 1u)) >> 16;   // RNE
  return (ushort)r;
}
static __device__ __forceinline__ float bf2f(ushort u) {
  return __builtin_bit_cast(float, (uint32_t)u << 16);
}

// fp32-exact (k*t) mod 1022 (k<=511, t<=1021: k*t < 2^24), then radians
static __device__ __forceinline__ float phase_mod(int k, int t) {
  const float TPN = 6.2831853071795864769f / 1022.f;
  float kt = (float)(k * t);
  float q = floorf(kt * (1.0f / 1022.0f));
  float r = kt - q * 1022.0f;
  if (r < 0.f) r += 1022.f;
  if (r >= 1022.f) r -= 1022.f;
  return r * TPN;
}

// ---------------- prep: BT1 (vec4) | A1-transpose ----------------
// blocks [0,1024): BT1[t][kk] (irfft basis * syn), 4 kk per thread
// blocks [1024,2048): A1 transpose tiles
__global__ __launch_bounds__(256) void prep(const float* __restrict__ x,
                                            ushort* __restrict__ BT1,
                                            ushort* __restrict__ A1) {
  __shared__ float tile[32][129];
  const float TPN = 6.2831853071795864769f / 1022.f;
  int bid = blockIdx.x;
  if (bid < 1024) {
    int idx4 = (bid * 256 + threadIdx.x) * 4;   // 4 consecutive kk, same t
    int t = idx4 >> 10, kk0 = idx4 & 1023;
    short4v v = (short4v){0, 0, 0, 0};
    if (t < NW) {
      float fw = 0.5f - 0.5f * __cosf((float)t * TPN);
      float den = 0.f;
      int tm = t & 255;
      #pragma unroll
      for (int j = 0; j < 4; ++j) {
        int u = tm + (j << 8);
        if (u < NW) { float w = 0.5f - 0.5f * __cosf((float)u * TPN); den += w * w; }
      }
      float syn = fw / den;
      #pragma unroll
      for (int e = 0; e < 4; ++e) {
        int kk = kk0 + e, k = kk & 511;
        float arg = phase_mod(k, t);
        float scale = (k == 0 || k == 511) ? 1.f : 2.f;
        float val;
        if (kk < 512) val = __cosf(arg) * scale * (1.f / 1022.f) * syn;
        else          val = (k == 0 || k == 511) ? 0.f
                            : -__sinf(arg) * scale * (1.f / 1022.f) * syn;
        v[e] = (short)f2bf(val);
      }
    }
    *(short4v*)&BT1[idx4] = v;
  } else {
    int tb = bid - 1024;
    int b  = tb >> 4;
    int k0 = (tb & 15) << 5;
    int tid = threadIdx.x;
    #pragma unroll
    for (int e = 0; e < 16; ++e) {
      int lin = tid + e * 256;
      int i = lin >> 7, c = lin & 127;
      tile[i][c] = x[(b * 512 + k0 + i) * 128 + c];
    }
    __syncthreads();
    #pragma unroll
    for (int e = 0; e < 16; ++e) {
      int lin = tid + e * 256;
      int c = lin >> 5, i = lin & 31;
      int f = c >> 1, ri = c & 1;
      A1[(b * 64 + f) * 1024 + ri * 512 + k0 + i] = f2bf(tile[i][c]);
    }
  }
}

// ---------------- shared GEMM pieces ----------------
#define GLOAD16(gsrc, ldst) \
  __builtin_amdgcn_global_load_lds( \
      (const __attribute__((address_space(1))) void*)(gsrc), \
      (__attribute__((address_space(3))) void*)(ldst), 16, 0, 0)

#define WAIT_VMCNT6()  __builtin_amdgcn_s_waitcnt(0xF76)  /* vmcnt(6) */
#define WAIT_VMCNT0()  __builtin_amdgcn_s_waitcnt(0xF70)  /* vmcnt(0) */

// wave-tile 32x64: acc[2][4]
static __device__ __forceinline__ void gemm_compute64(
    const ushort* as, const ushort* bs, int arow, int brow, int g, int rx,
    floatx4 (&acc)[2][4]) {
  #pragma unroll
  for (int ks = 0; ks < 2; ++ks) {
    short8 af[2], bfr[4];
    const int chunk = ((ks << 2) + g) ^ rx;
    #pragma unroll
    for (int fm = 0; fm < 2; ++fm)
      af[fm] = *(const short8*)(as + (arow + fm * 16) * 64 + chunk * 8);
    #pragma unroll
    for (int fn = 0; fn < 4; ++fn)
      bfr[fn] = *(const short8*)(bs + (brow + fn * 16) * 64 + chunk * 8);
    #pragma unroll
    for (int fm = 0; fm < 2; ++fm)
      #pragma unroll
      for (int fn = 0; fn < 4; ++fn)
        acc[fm][fn] = __builtin_amdgcn_mfma_f32_16x16x32_bf16(
            af[fm], bfr[fn], acc[fm][fn], 0, 0, 0);
  }
}

// ---- GEMM1: frames(bf16)[4096,1024] = A1 * BT1^T, XCD-swizzled; ----
// ---- plus rider blocks (by>=64, 1024 blocks) generating BT2 (vec4) ----
__global__ __launch_bounds__(256, 3) void gemm1(
    const ushort* __restrict__ A, const ushort* __restrict__ Bt,
    ushort* __restrict__ Fr, ushort* __restrict__ BT2) {
  __shared__ __align__(16) ushort As[2][64 * 64];
  __shared__ __align__(16) ushort Bs[2][128 * 64];
  const float TPN = 6.2831853071795864769f / 1022.f;

  if (blockIdx.y >= 64) {            // BT2 rider: 1024 blocks, 1M elems vec4
    int bid = (blockIdx.y - 64) * 8 + blockIdx.x;      // 0..1023
    int idx4 = (bid * 256 + threadIdx.x) * 4;          // 4 consecutive t, same kk
    int kk = idx4 >> 10, t0 = idx4 & 1023;
    int k = kk & 511;
    short4v v = (short4v){0, 0, 0, 0};
    #pragma unroll
    for (int e = 0; e < 4; ++e) {
      int t = t0 + e;
      if (t < NW) {
        float fw = 0.5f - 0.5f * __cosf((float)t * TPN);
        float arg = phase_mod(k, t);
        float val = (kk < 512) ? fw * __cosf(arg) : -fw * __sinf(arg);
        v[e] = (short)f2bf(val);
      }
    }
    *(short4v*)&BT2[idx4] = v;
    return;
  }

  // XCD-aware remap: cluster 8 m-panels per XCD so A stays L2-resident.
  const int L = blockIdx.x + 8 * blockIdx.y;   // 0..511
  const int xcd = L & 7, j = L >> 3;
  const int by_n = xcd * 8 + (j & 7);          // 0..63
  const int bx_n = j >> 3;                     // 0..7

  const int tid = threadIdx.x;
  const int wid = tid >> 6, lane = tid & 63;
  const int m0 = by_n * 64, n0 = bx_n * 128;
  const int warp_m = wid >> 1, warp_n = wid & 1;

  floatx4 acc[2][4];
  #pragma unroll
  for (int i = 0; i < 2; ++i)
    #pragma unroll
    for (int jj = 0; jj < 4; ++jj) acc[i][jj] = (floatx4){0.f, 0.f, 0.f, 0.f};

  const int lr = lane >> 3, lc = lane & 7;
  const int swz = lc ^ lr;
  const ushort* aBase = A  + (size_t)(m0 + wid * 8 + lr) * GK + swz * 8;
  const ushort* bBase = Bt + (size_t)(n0 + wid * 8 + lr) * GK + swz * 8;

  const int lane15 = lane & 15;
  const int g = lane >> 4;
  const int rx = lane & 7;
  const int arow = warp_m * 32 + lane15;
  const int brow = warp_n * 64 + lane15;

#define STAGE_G1(buf, kk0) do { \
    _Pragma("unroll") \
    for (int p = 0; p < 2; ++p) \
      GLOAD16(aBase + (size_t)(p * 32) * GK + (kk0), &As[buf][(p * 32 + wid * 8) * 64]); \
    _Pragma("unroll") \
    for (int p = 0; p < 4; ++p) \
      GLOAD16(bBase + (size_t)(p * 32) * GK + (kk0), &Bs[buf][(p * 32 + wid * 8) * 64]); \
    } while (0)

  STAGE_G1(0, 0);
  for (int t = 0; t < 15; ++t) {
    STAGE_G1((t + 1) & 1, (t + 1) * 64);
    WAIT_VMCNT6();
    __builtin_amdgcn_s_barrier();
    __builtin_amdgcn_sched_barrier(0);
    gemm_compute64(&As[t & 1][0], &Bs[t & 1][0], arow, brow, g, rx, acc);
    __builtin_amdgcn_sched_barrier(0);
    __builtin_amdgcn_s_barrier();
  }
  WAIT_VMCNT0();
  __builtin_amdgcn_s_barrier();
  gemm_compute64(&As[1][0], &Bs[1][0], arow, brow, g, rx, acc);

  #pragma unroll
  for (int fm = 0; fm < 2; ++fm)
    #pragma unroll
    for (int fn = 0; fn < 4; ++fn)
      #pragma unroll
      for (int i = 0; i < 4; ++i) {
        int gm = m0 + warp_m * 32 + fm * 16 + g * 4 + i;
        int gn = n0 + warp_n * 64 + fn * 16 + lane15;
        Fr[(size_t)gm * 1024 + gn] = f2bf(acc[fm][fn][i]);
      }
#undef STAGE_G1
}

// ---- GEMM2: out = gather(Ftb) * BT2^T, BM=64 (one batch/block), BN=128 ----
// XCD-swizzled: 8 batch rows clustered per XCD (A 275KB + B 2MB L2-resident)
__global__ __launch_bounds__(256, 3) void gemm2(
    const ushort* __restrict__ Ftb, const ushort* __restrict__ Bt,
    float* __restrict__ out) {
  __shared__ __align__(16) ushort smem[2 * 64 * 64 + 2 * 128 * 64];
  ushort (*As)[64 * 64] = (ushort(*)[64 * 64])smem;
  ushort (*Bs)[128 * 64] = (ushort(*)[128 * 64])(smem + 2 * 64 * 64);
  float* CT = (float*)smem;                     // [128][65] after compute
  const int tid = threadIdx.x;
  const int wid = tid >> 6, lane = tid & 63;

  // XCD-aware remap (bijective: 512 = 8 XCDs x 64)
  const int L = blockIdx.x + 8 * blockIdx.y;   // 0..511
  const int xcd = L & 7, j = L >> 3;
  const int by = xcd * 8 + (j & 7);            // batch b, 0..63
  const int bx = j >> 3;                       // k-block, 0..7

  const int warp_m = wid >> 1, warp_n = wid & 1;

  floatx4 acc[2][4];
  #pragma unroll
  for (int i = 0; i < 2; ++i)
    #pragma unroll
    for (int jj = 0; jj < 4; ++jj) acc[i][jj] = (floatx4){0.f, 0.f, 0.f, 0.f};

  const int lr = lane >> 3, lc = lane & 7;
  const int swz = lc ^ lr;

  const ushort* aBase = Ftb + (size_t)by * TLEN + (wid * 8 + lr) * 256 + swz * 8;
  const ushort* bB0 = Bt + (size_t)(bx * 64 + wid * 8 + lr) * GK + swz * 8;

  const int lane15 = lane & 15;
  const int g = lane >> 4;
  const int rx = lane & 7;
  const int arow = warp_m * 32 + lane15;
  const int brow = warp_n * 64 + lane15;

#define STAGE_G2(buf, kk0) do { \
    _Pragma("unroll") \
    for (int p = 0; p < 2; ++p) \
      GLOAD16(aBase + (size_t)(p * 32) * 256 + (kk0), &As[buf][(p * 32 + wid * 8) * 64]); \
    _Pragma("unroll") \
    for (int p = 0; p < 4; ++p) { \
      size_t boff = (size_t)((p & 1) * 32 + (p >> 1) * 512) * GK; \
      GLOAD16(bB0 + boff + (kk0), &Bs[buf][(((p >> 1) * 64 + (p & 1) * 32) + wid * 8) * 64]); \
    } } while (0)

  STAGE_G2(0, 0);
  for (int t = 0; t < 15; ++t) {
    STAGE_G2((t + 1) & 1, (t + 1) * 64);
    WAIT_VMCNT6();
    __builtin_amdgcn_s_barrier();
    __builtin_amdgcn_sched_barrier(0);
    gemm_compute64(&As[t & 1][0], &Bs[t & 1][0], arow, brow, g, rx, acc);
    __builtin_amdgcn_sched_barrier(0);
    __builtin_amdgcn_s_barrier();
  }
  WAIT_VMCNT0();
  __builtin_amdgcn_s_barrier();
  gemm_compute64(&As[1][0], &Bs[1][0], arow, brow, g, rx, acc);

  __syncthreads();
  #pragma unroll
  for (int fm = 0; fm < 2; ++fm)
    #pragma unroll
    for (int fn = 0; fn < 4; ++fn)
      #pragma unroll
      for (int i = 0; i < 4; ++i) {
        int s    = warp_n * 64 + fn * 16 + lane15;
        int fcol = warp_m * 32 + fm * 16 + g * 4 + i;
        CT[s * 65 + fcol] = acc[fm][fn][i];
      }
  __syncthreads();
  #pragma unroll
  for (int e = 0; e < 8; ++e) {
    int it = tid + e * 256;
    int r = it >> 5, q = it & 31;
    float4 v;
    v.x = CT[r * 65 + 2 * q];
    v.y = CT[(64 + r) * 65 + 2 * q];
    v.z = CT[r * 65 + 2 * q + 1];
    v.w = CT[(64 + r) * 65 + 2 * q + 1];
    *(float4*)&out[((size_t)(by * 512 + bx * 64 + r)) * 128 + q * 4] = v;
  }
#undef STAGE_G2
}

// ---------------- fused overlap-add + filtfilt -> bf16 signal ----------------
#define SWZ(r) ((r) ^ (((r) >> 6) & 31))

static __device__ __forceinline__ float oa_sample(const ushort* __restrict__ frb,
                                                  int tau) {
  int fhi = tau >> 8;
  int flo = fhi - 3; if (flo < 0) flo = 0;
  if (fhi > 63) fhi = 63;
  float sum = 0.f;
  for (int f = flo; f <= fhi; ++f) {
    int off = tau - (f << 8);
    if (off < NW) sum += bf2f(frb[(size_t)f * 1024 + off]);
  }
  return sum;
}

#define IIR_STEP(x, y)                                   \
  float y = fmaf(cf.b0, (x), z0);                        \
  z0 = fmaf(-cf.a1, y, fmaf(cf.b1, (x), z1));            \
  z1 = fmaf(-cf.a2, y, fmaf(cf.b2, (x), z2));            \
  z2 = fmaf(-cf.a3, y, fmaf(cf.b3, (x), z3));            \
  z3 = fmaf(-cf.a4, y, fmaf(cf.b4, (x), z4));            \
  z4 = fmaf(-cf.a5, y, cf.b5 * (x));

__global__ __launch_bounds__(256) void oa_iir(const ushort* __restrict__ Fr,
                                              ushort* __restrict__ Ftb,
                                              IirCoef cf) {
  __shared__ float bufX[SPAN];   // xe, later y2
  __shared__ float bufY[SPAN];   // y1
  const int blk = blockIdx.x;
  const int b = blk >> 3, sp = blk & 7;
  const int lo = sp * BS;
  const int hi = (lo + BS < TLEN) ? lo + BS : TLEN;     // filt range [lo,hi)
  const int F0 = (sp == 0) ? 0 : lo + PADL;             // fwd output xe-range
  int F1 = hi + PADL + 128; if (F1 > LXLEN) F1 = LXLEN;
  const int XB = (sp == 0) ? 0 : F0 - 64;               // xe LDS base
  const int xspan = F1 - XB;                            // <= SPAN
  const ushort* frb = Fr + (size_t)(b * 64) * 1024;

  // phase 1: xe -> bufX (reflect-pad over overlap-add, computed on the fly)
  for (int rel = threadIdx.x; rel < xspan; rel += 256) {
    int p = XB + rel;
    float v;
    if (p < PADL)
      v = 2.f * oa_sample(frb, 0) - oa_sample(frb, PADL - p);
    else if (p < PADL + TLEN)
      v = oa_sample(frb, p - PADL);
    else {
      int j = p - (PADL + TLEN);
      v = 2.f * oa_sample(frb, TLEN - 1) - oa_sample(frb, TLEN - 2 - j);
    }
    bufX[SWZ(rel)] = v;
  }
  __syncthreads();

  // phase 2: forward IIR chunks (64 warm + 64 live), bufX -> bufY
  {
    int nch = (F1 - F0 + 63) >> 6;
    int c = threadIdx.x;
    if (c < nch) {
      int os = F0 + (c << 6);
      int oe = os + 64; if (oe > F1) oe = F1;
      float z0, z1, z2, z3, z4;
      int i;
      if (sp == 0 && c == 0) {
        float x0 = bufX[SWZ(0)];
        z0 = cf.zi0 * x0; z1 = cf.zi1 * x0; z2 = cf.zi2 * x0;
        z3 = cf.zi3 * x0; z4 = cf.zi4 * x0;
        i = 0;
      } else {
        z0 = z1 = z2 = z3 = z4 = 0.f;
        i = os - 64;
        #pragma unroll 4
        for (; i < os; ++i) { float x = bufX[SWZ(i - XB)]; IIR_STEP(x, y); (void)y; }
      }
      #pragma unroll 4
      for (; i < oe; ++i) {
        float x = bufX[SWZ(i - XB)];
        IIR_STEP(x, y);
        bufY[SWZ(i - XB)] = y;
      }
    }
  }
  __syncthreads();

  // phase 3: backward IIR chunks (absolute 64-aligned reversed grid), bufY -> bufX
  {
    const int R0 = TLEN + PADL - hi;          // owned reversed range [R0, R1)
    const int R1 = LXLEN - lo - PADL;
    int k_lo = R0 >> 6, k_hi = (R1 - 1) >> 6;
    int k = k_lo + threadIdx.x;
    if (k <= k_hi) {
      int rs = k << 6;
      int re = rs + 64; if (re > R1) re = R1;
      float z0, z1, z2, z3, z4;
      int i;
      if (k == 0) {
        float x0 = bufY[SWZ(LXLEN - 1 - XB)];
        z0 = cf.zi0 * x0; z1 = cf.zi1 * x0; z2 = cf.zi2 * x0;
        z3 = cf.zi3 * x0; z4 = cf.zi4 * x0;
        i = 0;
      } else {
        z0 = z1 = z2 = z3 = z4 = 0.f;
        i = rs - 64;
        #pragma unroll 4
        for (; i < rs; ++i) { float x = bufY[SWZ(LXLEN - 1 - i - XB)]; IIR_STEP(x, y); (void)y; }
      }
      #pragma unroll 4
      for (; i < re; ++i) {
        float x = bufY[SWZ(LXLEN - 1 - i - XB)];
        IIR_STEP(x, y);
        if (i >= R0) bufX[SWZ(LXLEN - 1 - i - XB)] = y;
      }
    }
  }
  __syncthreads();

  // phase 4: coalesced bf16 write of owned filt range
  for (int t = lo + threadIdx.x; t < hi; t += 256)
    Ftb[(size_t)b * TLEN + t] = f2bf(bufX[SWZ(t + PADL - XB)]);
  // zero-pad tail so gemm2's K-padding reads stay finite
  if (b == NB - 1 && sp == NSPLIT - 1)
    for (int t = threadIdx.x; t < 1024; t += 256)
      Ftb[(size_t)NB * TLEN + t] = 0;
}

// ---------------- host: butter(5,0.5) + lfilter_zi ----------------
static void solve5(double M[5][5], double v[5], double outv[5]) {
  for (int col = 0; col < 5; ++col) {
    int piv = col;
    for (int r = col + 1; r < 5; ++r)
      if (std::fabs(M[r][col]) > std::fabs(M[piv][col])) piv = r;
    if (piv != col) {
      for (int c = 0; c < 5; ++c) std::swap(M[col][c], M[piv][c]);
      std::swap(v[col], v[piv]);
    }
    double d = M[col][col];
    for (int r = col + 1; r < 5; ++r) {
      double f = M[r][col] / d;
      for (int c = col; c < 5; ++c) M[r][c] -= f * M[col][c];
      v[r] -= f * v[col];
    }
  }
  for (int r = 4; r >= 0; --r) {
    double s = v[r];
    for (int c = r + 1; c < 5; ++c) s -= M[r][c] * outv[c];
    outv[r] = s / M[r][r];
  }
}

static IirCoef make_coef() {
  const double PI = 3.14159265358979323846;
  std::complex<double> p[5];
  for (int i = 0; i < 5; ++i) {
    double m = -4.0 + 2.0 * i;
    p[i] = -std::exp(std::complex<double>(0.0, PI * m / 10.0));
  }
  double fs = 2.0;
  double warped = 2.0 * fs * std::tan(PI * 0.5 / fs);
  for (int i = 0; i < 5; ++i) p[i] *= warped;
  double kgain = std::pow(warped, 5.0);
  double fs2 = 2.0 * fs;
  std::complex<double> pd[5], prod(1.0, 0.0);
  for (int i = 0; i < 5; ++i) {
    pd[i] = (fs2 + p[i]) / (fs2 - p[i]);
    prod *= (fs2 - p[i]);
  }
  double kd = kgain * std::real(1.0 / prod);
  double b[6] = {kd, 5 * kd, 10 * kd, 10 * kd, 5 * kd, kd};
  std::complex<double> c[6] = {{1,0},{0,0},{0,0},{0,0},{0,0},{0,0}};
  for (int i = 0; i < 5; ++i)
    for (int j = i + 1; j >= 1; --j)
      c[j] -= pd[i] * c[j - 1];
  double a[6]; for (int i = 0; i < 6; ++i) a[i] = c[i].real();
  double M[5][5], v[5];
  for (int r = 0; r < 5; ++r)
    for (int cc = 0; cc < 5; ++cc) {
      double Af = 0.0;
      if (cc == 0) Af = -a[r + 1];
      if (cc == r + 1) Af = 1.0;
      M[r][cc] = (r == cc ? 1.0 : 0.0) - Af;
    }
  for (int r = 0; r < 5; ++r) v[r] = b[r + 1] - a[r + 1] * b[0];
  double zi[5];
  solve5(M, v, zi);
  IirCoef cf;
  cf.b0 = (float)b[0]; cf.b1 = (float)b[1]; cf.b2 = (float)b[2];
  cf.b3 = (float)b[3]; cf.b4 = (float)b[4]; cf.b5 = (float)b[5];
  cf.a1 = (float)a[1]; cf.a2 = (float)a[2]; cf.a3 = (float)a[3];
  cf.a4 = (float)a[4]; cf.a5 = (float)a[5];
  cf.zi0 = (float)zi[0]; cf.zi1 = (float)zi[1]; cf.zi2 = (float)zi[2];
  cf.zi3 = (float)zi[3]; cf.zi4 = (float)zi[4];
  return cf;
}

extern "C" void kernel_launch(void* const* d_in, const int* in_sizes, int n_in,
                              void* d_out, int out_size, void* d_ws, size_t ws_size,
                              hipStream_t stream) {
  const float* x = (const float*)d_in[0];
  float* out = (float*)d_out;

  // workspace layout (bf16 everywhere except out)
  ushort* BT1 = (ushort*)d_ws;                   // 1024*1024
  ushort* BT2 = BT1 + 1024 * 1024;               // 1024*1024
  ushort* A1  = BT2 + 1024 * 1024;               // 4096*1024
  ushort* Ftb = A1 + (size_t)NFRAMES * 1024;     // NB*TLEN + 1024
  ushort* Fr  = Ftb + (size_t)NB * TLEN + 1024;  // 4096*1024 (bf16 frames)
  size_t need = (size_t)((char*)(Fr + (size_t)NFRAMES * 1024) - (char*)d_ws);
  if (ws_size < need) return;

  IirCoef cf = make_coef();

  prep<<<2048, 256, 0, stream>>>(x, BT1, A1);
  gemm1<<<dim3(8, 192), 256, 0, stream>>>(A1, BT1, Fr, BT2);
  oa_iir<<<NB * NSPLIT, 256, 0, stream>>>(Fr, Ftb, cf);
  gemm2<<<dim3(8, 64), 256, 0, stream>>>(Ftb, BT2, out);
}